// Round 1
// baseline (315.315 us; speedup 1.0000x reference)
//
#include <hip/hip_runtime.h>
#include <math.h>

#define NTOT 8388608   // 2^23 = 32*4096*64
#define N1   2048
#define N2   4096
#define BB   32
#define LL   4096
#define DD   64

__device__ inline float2 cmul(float2 a, float2 b) {
    return make_float2(a.x*b.x - a.y*b.y, a.x*b.y + a.y*b.x);
}

enum { M_NONE = 0, M_TW = 1, M_TWC = 2, M_H = 3, M_SCALE = 4 };

// ---------------- twiddle tables ----------------
// T1[j] = exp(-2*pi*i * j / 4096),   j in [0,4096)
// T2[b] = exp(-2*pi*i * b / 2^23),   b in [0,2048)
// exp(-2*pi*i*t/2^23) = T1[t>>11] * T2[t&2047]
__global__ __launch_bounds__(256) void gen_tables(float2* T1, float2* T2) {
    int j = blockIdx.x * 256 + threadIdx.x;
    if (j < 4096) {
        double ang = -2.0 * M_PI * (double)j / 4096.0;
        T1[j] = make_float2((float)cos(ang), (float)sin(ang));
    } else if (j < 4096 + 2048) {
        int b = j - 4096;
        double ang = -2.0 * M_PI * (double)b / 8388608.0;
        T2[b] = make_float2((float)cos(ang), (float)sin(ang));
    }
}

// ---------------- Stockham radix-2 FFT over contiguous rows, in place ----------------
template<int FFTN, int T, int LOG, bool INV, int MODE>
__global__ __launch_bounds__(T) void fft_rows(float2* data,
                                              const float2* __restrict__ T1tab,
                                              const float2* __restrict__ T2tab) {
    __shared__ float2 ping[FFTN];
    __shared__ float2 pong[FFTN];
    const int r   = blockIdx.x;
    const int tid = threadIdx.x;
    float2* base = data + (size_t)r * FFTN;

    #pragma unroll
    for (int k = 0; k < FFTN / T; ++k) ping[tid + k*T] = base[tid + k*T];
    __syncthreads();

    float2* src = ping;
    float2* dst = pong;
    #pragma unroll
    for (int st = 0; st < LOG; ++st) {
        const int s  = 1 << st;
        const int SH = 12 - LOG + st;          // twiddle index shift into 4096-root table
        #pragma unroll
        for (int k = 0; k < FFTN / 2 / T; ++k) {
            int id = tid + k*T;
            int p  = id >> st;
            int q  = id & (s - 1);
            float2 a = src[id];
            float2 b = src[id + FFTN/2];
            float2 w = T1tab[p << SH];
            if (INV) w.y = -w.y;
            float2 sum = make_float2(a.x + b.x, a.y + b.y);
            float2 dif = make_float2(a.x - b.x, a.y - b.y);
            float2 tw  = cmul(dif, w);
            int o = 2*id - q;
            dst[o]     = sum;
            dst[o + s] = tw;
        }
        __syncthreads();
        float2* tmp = src; src = dst; dst = tmp;
    }

    #pragma unroll
    for (int k = 0; k < FFTN / T; ++k) {
        int i = tid + k*T;
        float2 v = src[i];
        if (MODE == M_TW || MODE == M_TWC) {
            int t = r * i;                     // < 2^23, exact in int
            float2 w = cmul(T1tab[t >> 11], T2tab[t & 2047]);
            if (MODE == M_TWC) w.y = -w.y;
            v = cmul(v, w);
        } else if (MODE == M_H) {
            int kk = i * N2 + r;               // global frequency index k = k1*N2 + k2
            float hf = (kk == 0 || kk == NTOT/2) ? 1.f : (kk < NTOT/2 ? 2.f : 0.f);
            v.x *= hf; v.y *= hf;
        } else if (MODE == M_SCALE) {
            const float sc = 1.f / (float)NTOT;
            v.x *= sc; v.y *= sc;
        }
        base[i] = v;
    }
}

// ---------------- transposes ----------------
// x natural: n = n2*N1 + n1  -> viewed as [N2][N1] float.
// k_pre: A[n1][n2] = (max(x,0), max(-x,0))
__global__ __launch_bounds__(256) void k_pre(const float* __restrict__ x, float2* __restrict__ A) {
    __shared__ float tile[32][33];
    int c0 = blockIdx.x * 32;   // n1 tile
    int r0 = blockIdx.y * 32;   // n2 tile
    int tx = threadIdx.x, ty = threadIdx.y;
    #pragma unroll
    for (int j = 0; j < 32; j += 8)
        tile[ty + j][tx] = x[(size_t)(r0 + ty + j) * N1 + c0 + tx];
    __syncthreads();
    #pragma unroll
    for (int j = 0; j < 32; j += 8) {
        float v = tile[tx][ty + j];
        A[(size_t)(c0 + ty + j) * N2 + r0 + tx] = make_float2(fmaxf(v, 0.f), fmaxf(-v, 0.f));
    }
}

// generic complex transpose: out[c][r] = in[r][c];  grid = (inCols/32, inRows/32)
__global__ __launch_bounds__(256) void k_trans(const float2* __restrict__ in, float2* __restrict__ out,
                                               int inCols, int inRows) {
    __shared__ float2 tile[32][33];
    int c0 = blockIdx.x * 32;
    int r0 = blockIdx.y * 32;
    int tx = threadIdx.x, ty = threadIdx.y;
    #pragma unroll
    for (int j = 0; j < 32; j += 8)
        tile[ty + j][tx] = in[(size_t)(r0 + ty + j) * inCols + c0 + tx];
    __syncthreads();
    #pragma unroll
    for (int j = 0; j < 32; j += 8)
        out[(size_t)(c0 + ty + j) * inRows + r0 + tx] = tile[tx][ty + j];
}

// final transpose + envelope epilogue.
// A[n1][n2] holds w = ifft(h * fft(up + i*down)).  Natural n = n2*N1 + n1.
// Re(w) = up - H(down), Im(w) = H(up) + down.
__global__ __launch_bounds__(256) void k_post(const float2* __restrict__ A, const float* __restrict__ x,
                                              float* __restrict__ out) {
    __shared__ float2 tile[32][33];
    int c0 = blockIdx.x * 32;   // n2 tile (cols of A)
    int r0 = blockIdx.y * 32;   // n1 tile (rows of A)
    int tx = threadIdx.x, ty = threadIdx.y;
    #pragma unroll
    for (int j = 0; j < 32; j += 8)
        tile[ty + j][tx] = A[(size_t)(r0 + ty + j) * N2 + c0 + tx];
    __syncthreads();
    #pragma unroll
    for (int j = 0; j < 32; j += 8) {
        int n2 = c0 + ty + j;
        int n1 = r0 + tx;
        size_t n = (size_t)n2 * N1 + n1;
        float2 w = tile[tx][ty + j];
        float xv = x[n];
        float up = fmaxf(xv, 0.f);
        float dn = fmaxf(-xv, 0.f);
        float hu = w.y - dn;          // H(up)
        float hd = up - w.x;          // H(down)
        float em = sqrtf(up*up + hu*hu);    // envelope_max
        float en = sqrtf(dn*dn + hd*hd);    // -envelope_min
        float avg = 0.5f * (em - en);
        out[n]        = xv - avg;     // imf (unnormalized; scaled later)
        out[NTOT + n] = avg;          // avg_envelope
    }
}

// ---------------- std over L (ddof=1), then scale imf ----------------
// partials: grid = (BB * 16) blocks; block b*16+ch covers l in [ch*256, ch*256+256)
__global__ __launch_bounds__(256) void std_partial(const float* __restrict__ imf, float* __restrict__ part) {
    int blk = blockIdx.x;
    int b   = blk >> 4;
    int ch  = blk & 15;
    int d   = threadIdx.x & 63;
    int lw  = threadIdx.x >> 6;    // 0..3
    float s1 = 0.f, s2 = 0.f;
    const float* base = imf + (size_t)b * LL * DD;
    for (int i = 0; i < 64; ++i) {
        int l = ch * 256 + lw * 64 + i;
        float v = base[(size_t)l * DD + d];
        s1 += v;
        s2 += v * v;
    }
    __shared__ float r1[4][64];
    __shared__ float r2[4][64];
    r1[lw][d] = s1; r2[lw][d] = s2;
    __syncthreads();
    if (lw == 0) {
        s1 = r1[0][d] + r1[1][d] + r1[2][d] + r1[3][d];
        s2 = r2[0][d] + r2[1][d] + r2[2][d] + r2[3][d];
        int pi = blk * 64 + d;
        part[pi] = s1;
        part[BB * 16 * 64 + pi] = s2;
    }
}

__global__ __launch_bounds__(256) void std_final(const float* __restrict__ part, float* __restrict__ scalev) {
    int g = blockIdx.x * 256 + threadIdx.x;   // g = b*64 + d, 2048 total
    int b = g >> 6, d = g & 63;
    float s1 = 0.f, s2 = 0.f;
    for (int ch = 0; ch < 16; ++ch) {
        int pi = (b * 16 + ch) * 64 + d;
        s1 += part[pi];
        s2 += part[BB * 16 * 64 + pi];
    }
    float mean = s1 / (float)LL;
    float var  = (s2 - (float)LL * mean * mean) / (float)(LL - 1);
    var = fmaxf(var, 0.f);
    scalev[g] = 1.f / (sqrtf(var) + 0.01f);
}

__global__ __launch_bounds__(256) void apply_scale(float* __restrict__ out, const float* __restrict__ scalev) {
    size_t i = ((size_t)blockIdx.x * 256 + threadIdx.x) * 4;
    float4 v = *(float4*)(out + i);
    int b = (int)(i >> 18);          // L*D = 2^18
    int d = (int)(i & 63);
    const float* sc = scalev + b * 64;
    v.x *= sc[d];
    v.y *= sc[d + 1];
    v.z *= sc[d + 2];
    v.w *= sc[d + 3];
    *(float4*)(out + i) = v;
}

// ---------------- launch ----------------
extern "C" void kernel_launch(void* const* d_in, const int* in_sizes, int n_in,
                              void* d_out, int out_size, void* d_ws, size_t ws_size,
                              hipStream_t stream) {
    const float* x = (const float*)d_in[0];
    float* out = (float*)d_out;
    char* w = (char*)d_ws;

    float2* T1     = (float2*)w;                   // 32 KB
    float2* T2     = (float2*)(w + 32 * 1024);     // 16 KB
    float*  part   = (float*)(w + 48 * 1024);      // 256 KB
    float*  scalev = (float*)(w + 320 * 1024);     // 8 KB
    float2* A      = (float2*)(w + (1 << 20));     // 64 MB scratch
    float2* Bbuf   = (float2*)d_out;               // d_out doubles as the 2nd 64 MB buffer

    hipLaunchKernelGGL(gen_tables, dim3(24), dim3(256), 0, stream, T1, T2);

    // forward FFT of z = up + i*down (four-step, N = 2048*4096)
    hipLaunchKernelGGL(k_pre, dim3(N1/32, N2/32), dim3(32, 8), 0, stream, x, A);
    hipLaunchKernelGGL((fft_rows<4096, 512, 12, false, M_TW>), dim3(N1), dim3(512), 0, stream, A, T1, T2);
    hipLaunchKernelGGL(k_trans, dim3(N2/32, N1/32), dim3(32, 8), 0, stream, A, Bbuf, N2, N1);
    hipLaunchKernelGGL((fft_rows<2048, 256, 11, false, M_H>), dim3(N2), dim3(256), 0, stream, Bbuf, T1, T2);

    // inverse FFT of h*Z
    hipLaunchKernelGGL((fft_rows<2048, 256, 11, true, M_TWC>), dim3(N2), dim3(256), 0, stream, Bbuf, T1, T2);
    hipLaunchKernelGGL(k_trans, dim3(N1/32, N2/32), dim3(32, 8), 0, stream, Bbuf, A, N1, N2);
    hipLaunchKernelGGL((fft_rows<4096, 512, 12, true, M_SCALE>), dim3(N1), dim3(512), 0, stream, A, T1, T2);

    // epilogue: envelopes, imf, avg
    hipLaunchKernelGGL(k_post, dim3(N2/32, N1/32), dim3(32, 8), 0, stream, A, x, out);

    // std over L (ddof=1) and normalize imf in place
    hipLaunchKernelGGL(std_partial, dim3(BB * 16), dim3(256), 0, stream, out, part);
    hipLaunchKernelGGL(std_final, dim3(8), dim3(256), 0, stream, part, scalev);
    hipLaunchKernelGGL(apply_scale, dim3(NTOT / 4 / 256), dim3(256), 0, stream, out, scalev);
}

// Round 2
// 233.879 us; speedup vs baseline: 1.3482x; 1.3482x over previous
//
#include <hip/hip_runtime.h>
#include <math.h>

#define NTOT 8388608   // 2^23 = 32*4096*64
#define N1   2048
#define N2   4096
#define BB   32
#define LL   4096
#define DD   64

enum { M_NONE = 0, M_TW = 1, M_SCALE = 4 };

__device__ inline float2 cmul(float2 a, float2 b) {
    return make_float2(a.x*b.x - a.y*b.y, a.x*b.y + a.y*b.x);
}
__device__ inline float2 cadd(float2 a, float2 b){ return make_float2(a.x+b.x, a.y+b.y); }
__device__ inline float2 csub(float2 a, float2 b){ return make_float2(a.x-b.x, a.y-b.y); }
__device__ inline float2 mul_pi(float2 a){ return make_float2(-a.y, a.x); }   // * i
__device__ inline float2 mul_mi(float2 a){ return make_float2(a.y, -a.x); }   // * -i
__device__ inline int pidx(int a){ return a + (a >> 3); }                     // LDS pad

// DFT8: y_k = sum_m x_m W8^{+-km}
template<bool INV>
__device__ inline void dft8(const float2* x, float2* y) {
    const float C = 0.70710678118654752f;
    float2 t0=cadd(x[0],x[4]), t1=cadd(x[1],x[5]), t2=cadd(x[2],x[6]), t3=cadd(x[3],x[7]);
    float2 u0=csub(x[0],x[4]), u1=csub(x[1],x[5]), u2=csub(x[2],x[6]), u3=csub(x[3],x[7]);
    if (!INV) {
        u1 = make_float2(C*(u1.x+u1.y), C*(u1.y-u1.x));    // * (C,-C)
        u2 = mul_mi(u2);
        u3 = make_float2(C*(u3.y-u3.x), -C*(u3.x+u3.y));   // * (-C,-C)
    } else {
        u1 = make_float2(C*(u1.x-u1.y), C*(u1.y+u1.x));    // * (C,+C)
        u2 = mul_pi(u2);
        u3 = make_float2(-C*(u3.x+u3.y), C*(u3.x-u3.y));   // * (-C,+C)
    }
    {
        float2 s0=cadd(t0,t2), s1=cadd(t1,t3), d0=csub(t0,t2);
        float2 d1 = INV ? mul_pi(csub(t1,t3)) : mul_mi(csub(t1,t3));
        y[0]=cadd(s0,s1); y[4]=csub(s0,s1); y[2]=cadd(d0,d1); y[6]=csub(d0,d1);
    }
    {
        float2 s0=cadd(u0,u2), s1=cadd(u1,u3), d0=csub(u0,u2);
        float2 d1 = INV ? mul_pi(csub(u1,u3)) : mul_mi(csub(u1,u3));
        y[1]=cadd(s0,s1); y[5]=csub(s0,s1); y[3]=cadd(d0,d1); y[7]=csub(d0,d1);
    }
}

template<bool INV>
__device__ inline void dft4(const float2* u, float2* y) {
    float2 s0=cadd(u[0],u[2]), s1=cadd(u[1],u[3]), d0=csub(u[0],u[2]);
    float2 d1 = INV ? mul_pi(csub(u[1],u[3])) : mul_mi(csub(u[1],u[3]));
    y[0]=cadd(s0,s1); y[2]=csub(s0,s1); y[1]=cadd(d0,d1); y[3]=csub(d0,d1);
}

// y_k *= W_N^{ps*k}, N = 4096>>... : idx = (ps*k << SH) & 4095, T1[j]=W_4096^j
template<bool INV, int SH>
__device__ inline void twiddle8(float2* y, int ps, const float2* __restrict__ T1t) {
    #pragma unroll
    for (int k = 1; k < 8; ++k) {
        int idx = ((ps * k) << SH) & 4095;
        float2 w = T1t[idx];
        if (INV) w.y = -w.y;
        y[k] = cmul(y[k], w);
    }
}

// ---------------- twiddle tables ----------------
__global__ __launch_bounds__(256) void gen_tables(float2* T1, float2* T2) {
    int j = blockIdx.x * 256 + threadIdx.x;
    if (j < 4096) {
        double ang = -2.0 * M_PI * (double)j / 4096.0;
        T1[j] = make_float2((float)cos(ang), (float)sin(ang));
    } else if (j < 4096 + 2048) {
        int b = j - 4096;
        double ang = -2.0 * M_PI * (double)b / 8388608.0;
        T2[b] = make_float2((float)cos(ang), (float)sin(ang));
    }
}

// ---------------- 4096-point radix-8 Stockham, one row per block ----------------
template<bool INV, int MODE>
__global__ __launch_bounds__(512) void fft4096(float2* data,
                                               const float2* __restrict__ T1t,
                                               const float2* __restrict__ T2t) {
    __shared__ float SR[4608];
    __shared__ float SI[4608];
    const int t = threadIdx.x;
    const int r = blockIdx.x;
    float2* base = data + (size_t)r * 4096;

    float2 x[8], y[8];
    #pragma unroll
    for (int m = 0; m < 8; ++m) x[m] = base[t + 512*m];

    #pragma unroll
    for (int st = 0; st < 3; ++st) {
        const int s = 1 << (3*st);
        const int q = t & (s - 1);
        const int ps = t - q;
        dft8<INV>(x, y);
        twiddle8<INV, 0>(y, ps, T1t);
        if (st) __syncthreads();              // WAR vs previous reads
        #pragma unroll
        for (int k = 0; k < 8; ++k) {
            int a = 8*ps + q + k*s;
            SR[pidx(a)] = y[k].x; SI[pidx(a)] = y[k].y;
        }
        __syncthreads();
        #pragma unroll
        for (int m = 0; m < 8; ++m) {
            int a = t + 512*m;
            x[m] = make_float2(SR[pidx(a)], SI[pidx(a)]);
        }
    }
    // final stage: s=512, ps=0 -> no stage twiddle
    dft8<INV>(x, y);
    #pragma unroll
    for (int k = 0; k < 8; ++k) {
        int o = t + 512*k;
        float2 v = y[k];
        if (MODE == M_TW) {
            int tt = r * o;                   // <= 2047*4095 < 2^23
            float2 w = cmul(T1t[tt >> 11], T2t[tt & 2047]);
            if (INV) w.y = -w.y;
            v = cmul(v, w);
        } else if (MODE == M_SCALE) {
            const float sc = 1.f / 8388608.f;
            v.x *= sc; v.y *= sc;
        }
        base[o] = v;
    }
}

// ------- fused middle: fwd 2048 FFT + Hilbert mask + inv 2048 FFT + conj four-step twiddle -------
// rows r in [0,4096) of Bbuf[4096][2048]; global freq of row element i is k = i*N2 + r
__global__ __launch_bounds__(256) void fftmid(float2* data,
                                              const float2* __restrict__ T1t,
                                              const float2* __restrict__ T2t) {
    __shared__ float SR[2304];
    __shared__ float SI[2304];
    const int t = threadIdx.x;
    const int r = blockIdx.x;
    float2* base = data + (size_t)r * 2048;

    float2 x[8], y[8];
    #pragma unroll
    for (int m = 0; m < 8; ++m) x[m] = base[t + 256*m];

    // ---- forward: radix-8 stages s=1,8,64 ----
    #pragma unroll
    for (int st = 0; st < 3; ++st) {
        const int s = 1 << (3*st);
        const int q = t & (s - 1);
        const int ps = t - q;
        dft8<false>(x, y);
        twiddle8<false, 1>(y, ps, T1t);       // W_2048^{ps k} = T1[(2 ps k)&4095]
        if (st) __syncthreads();
        #pragma unroll
        for (int k = 0; k < 8; ++k) {
            int a = 8*ps + q + k*s;
            SR[pidx(a)] = y[k].x; SI[pidx(a)] = y[k].y;
        }
        __syncthreads();
        if (st < 2) {
            #pragma unroll
            for (int m = 0; m < 8; ++m) {
                int a = t + 256*m;
                x[m] = make_float2(SR[pidx(a)], SI[pidx(a)]);
            }
        }
    }
    // ---- forward final: radix-4, s=512, two ids per thread (t and t+256), ps=0 ----
    float2 xa[4], xb[4], ya[4], yb[4];
    #pragma unroll
    for (int m = 0; m < 4; ++m) {
        int a = t + 512*m;        xa[m] = make_float2(SR[pidx(a)], SI[pidx(a)]);
        int b = t + 256 + 512*m;  xb[m] = make_float2(SR[pidx(b)], SI[pidx(b)]);
    }
    dft4<false>(xa, ya);
    dft4<false>(xb, yb);
    __syncthreads();                           // WAR before mask write
    // ---- Hilbert mask at natural order, write back to LDS ----
    #pragma unroll
    for (int k = 0; k < 4; ++k) {
        int o = t + 512*k;                     // global freq = o*N2 + r
        float h = (o < 1024) ? ((o == 0 && r == 0) ? 1.f : 2.f)
                             : ((o == 1024 && r == 0) ? 1.f : 0.f);
        SR[pidx(o)] = ya[k].x * h; SI[pidx(o)] = ya[k].y * h;
        int o2 = o + 256;                      // o2 is never 0 or 1024
        float h2 = (o2 < 1024) ? 2.f : 0.f;
        SR[pidx(o2)] = yb[k].x * h2; SI[pidx(o2)] = yb[k].y * h2;
    }
    __syncthreads();
    // ---- inverse: radix-8 stages s=1,8,64 ----
    #pragma unroll
    for (int m = 0; m < 8; ++m) {
        int a = t + 256*m;
        x[m] = make_float2(SR[pidx(a)], SI[pidx(a)]);
    }
    #pragma unroll
    for (int st = 0; st < 3; ++st) {
        const int s = 1 << (3*st);
        const int q = t & (s - 1);
        const int ps = t - q;
        dft8<true>(x, y);
        twiddle8<true, 1>(y, ps, T1t);
        __syncthreads();                       // WAR (incl. st=0 vs mask reads)
        #pragma unroll
        for (int k = 0; k < 8; ++k) {
            int a = 8*ps + q + k*s;
            SR[pidx(a)] = y[k].x; SI[pidx(a)] = y[k].y;
        }
        __syncthreads();
        if (st < 2) {
            #pragma unroll
            for (int m = 0; m < 8; ++m) {
                int a = t + 256*m;
                x[m] = make_float2(SR[pidx(a)], SI[pidx(a)]);
            }
        }
    }
    // ---- inverse final: radix-4 + conj four-step twiddle + store ----
    #pragma unroll
    for (int m = 0; m < 4; ++m) {
        int a = t + 512*m;        xa[m] = make_float2(SR[pidx(a)], SI[pidx(a)]);
        int b = t + 256 + 512*m;  xb[m] = make_float2(SR[pidx(b)], SI[pidx(b)]);
    }
    dft4<true>(xa, ya);
    dft4<true>(xb, yb);
    #pragma unroll
    for (int k = 0; k < 4; ++k) {
        int o = t + 512*k;
        int tt = r * o;                        // <= 4095*2047 < 2^23
        float2 w = cmul(T1t[tt >> 11], T2t[tt & 2047]);
        w.y = -w.y;
        base[o] = cmul(ya[k], w);
        int o2 = o + 256;
        int tt2 = r * o2;
        float2 w2 = cmul(T1t[tt2 >> 11], T2t[tt2 & 2047]);
        w2.y = -w2.y;
        base[o2] = cmul(yb[k], w2);
    }
}

// ---------------- transposes ----------------
__global__ __launch_bounds__(256) void k_pre(const float* __restrict__ x, float2* __restrict__ A) {
    __shared__ float tile[32][33];
    int c0 = blockIdx.x * 32;   // n1 tile
    int r0 = blockIdx.y * 32;   // n2 tile
    int tx = threadIdx.x, ty = threadIdx.y;
    #pragma unroll
    for (int j = 0; j < 32; j += 8)
        tile[ty + j][tx] = x[(size_t)(r0 + ty + j) * N1 + c0 + tx];
    __syncthreads();
    #pragma unroll
    for (int j = 0; j < 32; j += 8) {
        float v = tile[tx][ty + j];
        A[(size_t)(c0 + ty + j) * N2 + r0 + tx] = make_float2(fmaxf(v, 0.f), fmaxf(-v, 0.f));
    }
}

__global__ __launch_bounds__(256) void k_trans(const float2* __restrict__ in, float2* __restrict__ out,
                                               int inCols, int inRows) {
    __shared__ float2 tile[32][33];
    int c0 = blockIdx.x * 32;
    int r0 = blockIdx.y * 32;
    int tx = threadIdx.x, ty = threadIdx.y;
    #pragma unroll
    for (int j = 0; j < 32; j += 8)
        tile[ty + j][tx] = in[(size_t)(r0 + ty + j) * inCols + c0 + tx];
    __syncthreads();
    #pragma unroll
    for (int j = 0; j < 32; j += 8)
        out[(size_t)(c0 + ty + j) * inRows + r0 + tx] = tile[tx][ty + j];
}

__global__ __launch_bounds__(256) void k_post(const float2* __restrict__ A, const float* __restrict__ x,
                                              float* __restrict__ out) {
    __shared__ float2 tile[32][33];
    int c0 = blockIdx.x * 32;   // n2 tile
    int r0 = blockIdx.y * 32;   // n1 tile
    int tx = threadIdx.x, ty = threadIdx.y;
    #pragma unroll
    for (int j = 0; j < 32; j += 8)
        tile[ty + j][tx] = A[(size_t)(r0 + ty + j) * N2 + c0 + tx];
    __syncthreads();
    #pragma unroll
    for (int j = 0; j < 32; j += 8) {
        int n2 = c0 + ty + j;
        int n1 = r0 + tx;
        size_t n = (size_t)n2 * N1 + n1;
        float2 w = tile[tx][ty + j];
        float xv = x[n];
        float up = fmaxf(xv, 0.f);
        float dn = fmaxf(-xv, 0.f);
        float hu = w.y - dn;          // H(up)
        float hd = up - w.x;          // H(down)
        float em = sqrtf(up*up + hu*hu);
        float en = sqrtf(dn*dn + hd*hd);
        float avg = 0.5f * (em - en);
        out[n]        = xv - avg;
        out[NTOT + n] = avg;
    }
}

// ---------------- std over L (ddof=1), then scale imf ----------------
__global__ __launch_bounds__(256) void std_partial(const float* __restrict__ imf, float* __restrict__ part) {
    int blk = blockIdx.x;
    int b   = blk >> 4;
    int ch  = blk & 15;
    int d   = threadIdx.x & 63;
    int lw  = threadIdx.x >> 6;
    float s1 = 0.f, s2 = 0.f;
    const float* base = imf + (size_t)b * LL * DD;
    for (int i = 0; i < 64; ++i) {
        int l = ch * 256 + lw * 64 + i;
        float v = base[(size_t)l * DD + d];
        s1 += v;
        s2 += v * v;
    }
    __shared__ float r1[4][64];
    __shared__ float r2[4][64];
    r1[lw][d] = s1; r2[lw][d] = s2;
    __syncthreads();
    if (lw == 0) {
        s1 = r1[0][d] + r1[1][d] + r1[2][d] + r1[3][d];
        s2 = r2[0][d] + r2[1][d] + r2[2][d] + r2[3][d];
        int pi = blk * 64 + d;
        part[pi] = s1;
        part[BB * 16 * 64 + pi] = s2;
    }
}

__global__ __launch_bounds__(256) void std_final(const float* __restrict__ part, float* __restrict__ scalev) {
    int g = blockIdx.x * 256 + threadIdx.x;
    int b = g >> 6, d = g & 63;
    float s1 = 0.f, s2 = 0.f;
    for (int ch = 0; ch < 16; ++ch) {
        int pi = (b * 16 + ch) * 64 + d;
        s1 += part[pi];
        s2 += part[BB * 16 * 64 + pi];
    }
    float mean = s1 / (float)LL;
    float var  = (s2 - (float)LL * mean * mean) / (float)(LL - 1);
    var = fmaxf(var, 0.f);
    scalev[g] = 1.f / (sqrtf(var) + 0.01f);
}

__global__ __launch_bounds__(256) void apply_scale(float* __restrict__ out, const float* __restrict__ scalev) {
    size_t i = ((size_t)blockIdx.x * 256 + threadIdx.x) * 4;
    float4 v = *(float4*)(out + i);
    int b = (int)(i >> 18);
    int d = (int)(i & 63);
    const float* sc = scalev + b * 64;
    v.x *= sc[d];
    v.y *= sc[d + 1];
    v.z *= sc[d + 2];
    v.w *= sc[d + 3];
    *(float4*)(out + i) = v;
}

// ---------------- launch ----------------
extern "C" void kernel_launch(void* const* d_in, const int* in_sizes, int n_in,
                              void* d_out, int out_size, void* d_ws, size_t ws_size,
                              hipStream_t stream) {
    const float* x = (const float*)d_in[0];
    float* out = (float*)d_out;
    char* w = (char*)d_ws;

    float2* T1     = (float2*)w;
    float2* T2     = (float2*)(w + 32 * 1024);
    float*  part   = (float*)(w + 48 * 1024);
    float*  scalev = (float*)(w + 320 * 1024);
    float2* A      = (float2*)(w + (1 << 20));
    float2* Bbuf   = (float2*)d_out;

    hipLaunchKernelGGL(gen_tables, dim3(24), dim3(256), 0, stream, T1, T2);

    hipLaunchKernelGGL(k_pre, dim3(N1/32, N2/32), dim3(32, 8), 0, stream, x, A);
    hipLaunchKernelGGL((fft4096<false, M_TW>), dim3(N1), dim3(512), 0, stream, A, T1, T2);
    hipLaunchKernelGGL(k_trans, dim3(N2/32, N1/32), dim3(32, 8), 0, stream, A, Bbuf, N2, N1);
    hipLaunchKernelGGL(fftmid, dim3(N2), dim3(256), 0, stream, Bbuf, T1, T2);
    hipLaunchKernelGGL(k_trans, dim3(N1/32, N2/32), dim3(32, 8), 0, stream, Bbuf, A, N1, N2);
    hipLaunchKernelGGL((fft4096<true, M_SCALE>), dim3(N1), dim3(512), 0, stream, A, T1, T2);
    hipLaunchKernelGGL(k_post, dim3(N2/32, N1/32), dim3(32, 8), 0, stream, A, x, out);

    hipLaunchKernelGGL(std_partial, dim3(BB * 16), dim3(256), 0, stream, out, part);
    hipLaunchKernelGGL(std_final, dim3(8), dim3(256), 0, stream, part, scalev);
    hipLaunchKernelGGL(apply_scale, dim3(NTOT / 4 / 256), dim3(256), 0, stream, out, scalev);
}

// Round 3
// 231.615 us; speedup vs baseline: 1.3614x; 1.0098x over previous
//
#include <hip/hip_runtime.h>
#include <math.h>

#define NTOT 8388608   // 2^23 = 32*4096*64
#define N1   2048
#define N2   4096
#define BB   32
#define LL   4096
#define DD   64

enum { M_NONE = 0, M_TW = 1, M_SCALE = 4 };

__device__ inline float2 cmul(float2 a, float2 b) {
    return make_float2(a.x*b.x - a.y*b.y, a.x*b.y + a.y*b.x);
}
__device__ inline float2 cmul_conj(float2 a, float2 b) {   // a * conj(b)
    return make_float2(a.x*b.x + a.y*b.y, a.y*b.x - a.x*b.y);
}
__device__ inline float2 cadd(float2 a, float2 b){ return make_float2(a.x+b.x, a.y+b.y); }
__device__ inline float2 csub(float2 a, float2 b){ return make_float2(a.x-b.x, a.y-b.y); }
__device__ inline float2 mul_pi(float2 a){ return make_float2(-a.y, a.x); }   // * i
__device__ inline float2 mul_mi(float2 a){ return make_float2(a.y, -a.x); }   // * -i
__device__ inline int pidx(int a){ return a + (a >> 4); }                     // float2 LDS pad

// DFT8: y_k = sum_m x_m W8^{+-km}
template<bool INV>
__device__ inline void dft8(const float2* x, float2* y) {
    const float C = 0.70710678118654752f;
    float2 t0=cadd(x[0],x[4]), t1=cadd(x[1],x[5]), t2=cadd(x[2],x[6]), t3=cadd(x[3],x[7]);
    float2 u0=csub(x[0],x[4]), u1=csub(x[1],x[5]), u2=csub(x[2],x[6]), u3=csub(x[3],x[7]);
    if (!INV) {
        u1 = make_float2(C*(u1.x+u1.y), C*(u1.y-u1.x));
        u2 = mul_mi(u2);
        u3 = make_float2(C*(u3.y-u3.x), -C*(u3.x+u3.y));
    } else {
        u1 = make_float2(C*(u1.x-u1.y), C*(u1.y+u1.x));
        u2 = mul_pi(u2);
        u3 = make_float2(-C*(u3.x+u3.y), C*(u3.x-u3.y));
    }
    {
        float2 s0=cadd(t0,t2), s1=cadd(t1,t3), d0=csub(t0,t2);
        float2 d1 = INV ? mul_pi(csub(t1,t3)) : mul_mi(csub(t1,t3));
        y[0]=cadd(s0,s1); y[4]=csub(s0,s1); y[2]=cadd(d0,d1); y[6]=csub(d0,d1);
    }
    {
        float2 s0=cadd(u0,u2), s1=cadd(u1,u3), d0=csub(u0,u2);
        float2 d1 = INV ? mul_pi(csub(u1,u3)) : mul_mi(csub(u1,u3));
        y[1]=cadd(s0,s1); y[5]=csub(s0,s1); y[3]=cadd(d0,d1); y[7]=csub(d0,d1);
    }
}

// inverse DFT8 with x[4..7] == 0 (Hilbert-zeroed upper half)
__device__ inline void dft8_h0_inv(const float2* x, float2* y) {
    const float C = 0.70710678118654752f;
    float2 u1 = make_float2(C*(x[1].x - x[1].y), C*(x[1].y + x[1].x));
    float2 u2 = mul_pi(x[2]);
    float2 u3 = make_float2(-C*(x[3].x + x[3].y), C*(x[3].x - x[3].y));
    {
        float2 s0=cadd(x[0],x[2]), s1=cadd(x[1],x[3]), d0=csub(x[0],x[2]);
        float2 d1 = mul_pi(csub(x[1],x[3]));
        y[0]=cadd(s0,s1); y[4]=csub(s0,s1); y[2]=cadd(d0,d1); y[6]=csub(d0,d1);
    }
    {
        float2 s0=cadd(x[0],u2), s1=cadd(u1,u3), d0=csub(x[0],u2);
        float2 d1 = mul_pi(csub(u1,u3));
        y[1]=cadd(s0,s1); y[5]=csub(s0,s1); y[3]=cadd(d0,d1); y[7]=csub(d0,d1);
    }
}

template<bool INV>
__device__ inline void dft4(const float2* u, float2* y) {
    float2 s0=cadd(u[0],u[2]), s1=cadd(u[1],u[3]), d0=csub(u[0],u[2]);
    float2 d1 = INV ? mul_pi(csub(u[1],u[3])) : mul_mi(csub(u[1],u[3]));
    y[0]=cadd(s0,s1); y[2]=csub(s0,s1); y[1]=cadd(d0,d1); y[3]=csub(d0,d1);
}

// y_k *= W^{+-ps*k}: idx = (ps*k << SH) & 4095, T1[j]=W_4096^j (SH=0 -> N=4096, SH=1 -> N=2048)
template<bool INV, int SH>
__device__ inline void twiddle8(float2* y, int ps, const float2* __restrict__ T1t) {
    #pragma unroll
    for (int k = 1; k < 8; ++k) {
        int idx = ((ps * k) << SH) & 4095;
        float2 w = T1t[idx];
        y[k] = INV ? cmul_conj(y[k], w) : cmul(y[k], w);
    }
}

// ---------------- twiddle tables ----------------
__global__ __launch_bounds__(256) void gen_tables(float2* T1, float2* T2) {
    int j = blockIdx.x * 256 + threadIdx.x;
    if (j < 4096) {
        double ang = -2.0 * M_PI * (double)j / 4096.0;
        T1[j] = make_float2((float)cos(ang), (float)sin(ang));
    } else if (j < 4096 + 2048) {
        int b = j - 4096;
        double ang = -2.0 * M_PI * (double)b / 8388608.0;
        T2[b] = make_float2((float)cos(ang), (float)sin(ang));
    }
}

// ---------------- 4096-point radix-8 Stockham, one row per block ----------------
template<bool INV, int MODE>
__global__ __launch_bounds__(512) void fft4096(float2* data,
                                               const float2* __restrict__ T1t,
                                               const float2* __restrict__ T2t) {
    __shared__ float2 S[4352];
    const int t = threadIdx.x;
    const int r = blockIdx.x;
    float2* base = data + (size_t)r * 4096;

    float2 x[8], y[8];
    #pragma unroll
    for (int m = 0; m < 8; ++m) x[m] = base[t + 512*m];

    #pragma unroll
    for (int st = 0; st < 3; ++st) {
        const int s = 1 << (3*st);
        const int q = t & (s - 1);
        const int ps = t - q;
        dft8<INV>(x, y);
        twiddle8<INV, 0>(y, ps, T1t);
        if (st) __syncthreads();
        #pragma unroll
        for (int k = 0; k < 8; ++k) S[pidx(8*ps + q + k*s)] = y[k];
        __syncthreads();
        #pragma unroll
        for (int m = 0; m < 8; ++m) x[m] = S[pidx(t + 512*m)];
    }
    dft8<INV>(x, y);
    #pragma unroll
    for (int k = 0; k < 8; ++k) {
        int o = t + 512*k;
        float2 v = y[k];
        if (MODE == M_TW) {
            int tt = r * o;                    // <= 2047*4095 < 2^23
            float2 w = cmul(T1t[tt >> 11], T2t[tt & 2047]);
            v = INV ? cmul_conj(v, w) : cmul(v, w);
        } else if (MODE == M_SCALE) {
            const float sc = 1.f / 8388608.f;
            v.x *= sc; v.y *= sc;
        }
        base[o] = v;
    }
}

// ------- fused middle: fwd 2048 FFT + Hilbert mask + inv 2048 FFT + conj four-step twiddle -------
// rows r in [0,4096); global freq of row element i is k = i*N2 + r
__global__ __launch_bounds__(256) void fftmid(float2* data,
                                              const float2* __restrict__ T1t,
                                              const float2* __restrict__ T2t) {
    __shared__ float2 S[2176];
    const int t = threadIdx.x;
    const int r = blockIdx.x;
    float2* base = data + (size_t)r * 2048;

    float2 x[8], y[8];
    #pragma unroll
    for (int m = 0; m < 8; ++m) x[m] = base[t + 256*m];

    // ---- forward: radix-8 stages s=1,8,64 ----
    #pragma unroll
    for (int st = 0; st < 3; ++st) {
        const int s = 1 << (3*st);
        const int q = t & (s - 1);
        const int ps = t - q;
        dft8<false>(x, y);
        twiddle8<false, 1>(y, ps, T1t);
        if (st) __syncthreads();
        #pragma unroll
        for (int k = 0; k < 8; ++k) S[pidx(8*ps + q + k*s)] = y[k];
        __syncthreads();
        if (st < 2) {
            #pragma unroll
            for (int m = 0; m < 8; ++m) x[m] = S[pidx(t + 256*m)];
        }
    }
    // ---- forward final: radix-4, s=512, ids t and t+256, ps=0 ----
    float2 xa[4], xb[4], ya[4], yb[4];
    #pragma unroll
    for (int m = 0; m < 4; ++m) {
        xa[m] = S[pidx(t + 512*m)];
        xb[m] = S[pidx(t + 256 + 512*m)];
    }
    dft4<false>(xa, ya);
    dft4<false>(xb, yb);
    __syncthreads();                           // WAR before mask writes
    // ---- Hilbert mask at natural order; only o <= 1024 survives ----
    #pragma unroll
    for (int k = 0; k < 4; ++k) {
        int o = t + 512*k;                     // global freq = o*N2 + r
        if (o < 1024) {
            float h = (o == 0 && r == 0) ? 1.f : 2.f;
            S[pidx(o)] = make_float2(ya[k].x * h, ya[k].y * h);
        } else if (o == 1024) {                // t==0, k==2
            S[pidx(1024)] = (r == 0) ? ya[k] : make_float2(0.f, 0.f);
        }
        int o2 = o + 256;                      // never 0 or 1024
        if (o2 < 1024) S[pidx(o2)] = make_float2(yb[k].x * 2.f, yb[k].y * 2.f);
    }
    __syncthreads();
    // ---- inverse stage 0 (s=1, ps=t): upper half is zero ----
    #pragma unroll
    for (int m = 0; m < 4; ++m) x[m] = S[pidx(t + 256*m)];
    dft8_h0_inv(x, y);
    if (t == 0) {                              // corner: freq o=1024 (h=1, r==0 only)
        float2 c = S[pidx(1024)];
        #pragma unroll
        for (int k = 0; k < 8; ++k) {
            if (k & 1) { y[k].x -= c.x; y[k].y -= c.y; }
            else       { y[k].x += c.x; y[k].y += c.y; }
        }
    }
    twiddle8<true, 1>(y, t, T1t);
    __syncthreads();                           // WAR vs masked reads
    #pragma unroll
    for (int k = 0; k < 8; ++k) S[pidx(8*t + k)] = y[k];
    __syncthreads();
    // ---- inverse stages s=8,64 ----
    #pragma unroll
    for (int st = 1; st < 3; ++st) {
        const int s = 1 << (3*st);
        const int q = t & (s - 1);
        const int ps = t - q;
        #pragma unroll
        for (int m = 0; m < 8; ++m) x[m] = S[pidx(t + 256*m)];
        dft8<true>(x, y);
        twiddle8<true, 1>(y, ps, T1t);
        __syncthreads();
        #pragma unroll
        for (int k = 0; k < 8; ++k) S[pidx(8*ps + q + k*s)] = y[k];
        __syncthreads();
    }
    // ---- inverse final: radix-4 + conj four-step twiddle + store ----
    #pragma unroll
    for (int m = 0; m < 4; ++m) {
        xa[m] = S[pidx(t + 512*m)];
        xb[m] = S[pidx(t + 256 + 512*m)];
    }
    dft4<true>(xa, ya);
    dft4<true>(xb, yb);
    #pragma unroll
    for (int k = 0; k < 4; ++k) {
        int o = t + 512*k;
        int tt = r * o;                        // <= 4095*2047 < 2^23
        float2 w = cmul(T1t[tt >> 11], T2t[tt & 2047]);
        base[o] = cmul_conj(ya[k], w);
        int o2 = o + 256;
        int tt2 = r * o2;
        float2 w2 = cmul(T1t[tt2 >> 11], T2t[tt2 & 2047]);
        base[o2] = cmul_conj(yb[k], w2);
    }
}

// ---------------- transposes ----------------
__global__ __launch_bounds__(256) void k_pre(const float* __restrict__ x, float2* __restrict__ A) {
    __shared__ float tile[32][33];
    int c0 = blockIdx.x * 32;   // n1 tile
    int r0 = blockIdx.y * 32;   // n2 tile
    int tx = threadIdx.x, ty = threadIdx.y;
    #pragma unroll
    for (int j = 0; j < 32; j += 8)
        tile[ty + j][tx] = x[(size_t)(r0 + ty + j) * N1 + c0 + tx];
    __syncthreads();
    #pragma unroll
    for (int j = 0; j < 32; j += 8) {
        float v = tile[tx][ty + j];
        A[(size_t)(c0 + ty + j) * N2 + r0 + tx] = make_float2(fmaxf(v, 0.f), fmaxf(-v, 0.f));
    }
}

__global__ __launch_bounds__(256) void k_trans(const float2* __restrict__ in, float2* __restrict__ out,
                                               int inCols, int inRows) {
    __shared__ float2 tile[32][33];
    int c0 = blockIdx.x * 32;
    int r0 = blockIdx.y * 32;
    int tx = threadIdx.x, ty = threadIdx.y;
    #pragma unroll
    for (int j = 0; j < 32; j += 8)
        tile[ty + j][tx] = in[(size_t)(r0 + ty + j) * inCols + c0 + tx];
    __syncthreads();
    #pragma unroll
    for (int j = 0; j < 32; j += 8)
        out[(size_t)(c0 + ty + j) * inRows + r0 + tx] = tile[tx][ty + j];
}

__global__ __launch_bounds__(256) void k_post(const float2* __restrict__ A, const float* __restrict__ x,
                                              float* __restrict__ out) {
    __shared__ float2 tile[32][33];
    int c0 = blockIdx.x * 32;   // n2 tile
    int r0 = blockIdx.y * 32;   // n1 tile
    int tx = threadIdx.x, ty = threadIdx.y;
    #pragma unroll
    for (int j = 0; j < 32; j += 8)
        tile[ty + j][tx] = A[(size_t)(r0 + ty + j) * N2 + c0 + tx];
    __syncthreads();
    #pragma unroll
    for (int j = 0; j < 32; j += 8) {
        int n2 = c0 + ty + j;
        int n1 = r0 + tx;
        size_t n = (size_t)n2 * N1 + n1;
        float2 w = tile[tx][ty + j];
        float xv = x[n];
        float up = fmaxf(xv, 0.f);
        float dn = fmaxf(-xv, 0.f);
        float hu = w.y - dn;          // H(up)
        float hd = up - w.x;          // H(down)
        float em = sqrtf(up*up + hu*hu);
        float en = sqrtf(dn*dn + hd*hd);
        float avg = 0.5f * (em - en);
        out[n]        = xv - avg;
        out[NTOT + n] = avg;
    }
}

// ---------------- std over L (ddof=1), then scale imf ----------------
__global__ __launch_bounds__(256) void std_partial(const float* __restrict__ imf, float* __restrict__ part) {
    int blk = blockIdx.x;
    int b   = blk >> 4;
    int ch  = blk & 15;
    int d   = threadIdx.x & 63;
    int lw  = threadIdx.x >> 6;
    float s1 = 0.f, s2 = 0.f;
    const float* base = imf + (size_t)b * LL * DD;
    for (int i = 0; i < 64; ++i) {
        int l = ch * 256 + lw * 64 + i;
        float v = base[(size_t)l * DD + d];
        s1 += v;
        s2 += v * v;
    }
    __shared__ float r1[4][64];
    __shared__ float r2[4][64];
    r1[lw][d] = s1; r2[lw][d] = s2;
    __syncthreads();
    if (lw == 0) {
        s1 = r1[0][d] + r1[1][d] + r1[2][d] + r1[3][d];
        s2 = r2[0][d] + r2[1][d] + r2[2][d] + r2[3][d];
        int pi = blk * 64 + d;
        part[pi] = s1;
        part[BB * 16 * 64 + pi] = s2;
    }
}

__global__ __launch_bounds__(256) void std_final(const float* __restrict__ part, float* __restrict__ scalev) {
    int g = blockIdx.x * 256 + threadIdx.x;
    int b = g >> 6, d = g & 63;
    float s1 = 0.f, s2 = 0.f;
    for (int ch = 0; ch < 16; ++ch) {
        int pi = (b * 16 + ch) * 64 + d;
        s1 += part[pi];
        s2 += part[BB * 16 * 64 + pi];
    }
    float mean = s1 / (float)LL;
    float var  = (s2 - (float)LL * mean * mean) / (float)(LL - 1);
    var = fmaxf(var, 0.f);
    scalev[g] = 1.f / (sqrtf(var) + 0.01f);
}

__global__ __launch_bounds__(256) void apply_scale(float* __restrict__ out, const float* __restrict__ scalev) {
    size_t i = ((size_t)blockIdx.x * 256 + threadIdx.x) * 4;
    float4 v = *(float4*)(out + i);
    int b = (int)(i >> 18);
    int d = (int)(i & 63);
    const float* sc = scalev + b * 64;
    v.x *= sc[d];
    v.y *= sc[d + 1];
    v.z *= sc[d + 2];
    v.w *= sc[d + 3];
    *(float4*)(out + i) = v;
}

// ---------------- launch ----------------
extern "C" void kernel_launch(void* const* d_in, const int* in_sizes, int n_in,
                              void* d_out, int out_size, void* d_ws, size_t ws_size,
                              hipStream_t stream) {
    const float* x = (const float*)d_in[0];
    float* out = (float*)d_out;
    char* w = (char*)d_ws;

    float2* T1     = (float2*)w;
    float2* T2     = (float2*)(w + 32 * 1024);
    float*  part   = (float*)(w + 48 * 1024);
    float*  scalev = (float*)(w + 320 * 1024);
    float2* A      = (float2*)(w + (1 << 20));
    float2* Bbuf   = (float2*)d_out;

    hipLaunchKernelGGL(gen_tables, dim3(24), dim3(256), 0, stream, T1, T2);

    hipLaunchKernelGGL(k_pre, dim3(N1/32, N2/32), dim3(32, 8), 0, stream, x, A);
    hipLaunchKernelGGL((fft4096<false, M_TW>), dim3(N1), dim3(512), 0, stream, A, T1, T2);
    hipLaunchKernelGGL(k_trans, dim3(N2/32, N1/32), dim3(32, 8), 0, stream, A, Bbuf, N2, N1);
    hipLaunchKernelGGL(fftmid, dim3(N2), dim3(256), 0, stream, Bbuf, T1, T2);
    hipLaunchKernelGGL(k_trans, dim3(N1/32, N2/32), dim3(32, 8), 0, stream, Bbuf, A, N1, N2);
    hipLaunchKernelGGL((fft4096<true, M_SCALE>), dim3(N1), dim3(512), 0, stream, A, T1, T2);
    hipLaunchKernelGGL(k_post, dim3(N2/32, N1/32), dim3(32, 8), 0, stream, A, x, out);

    hipLaunchKernelGGL(std_partial, dim3(BB * 16), dim3(256), 0, stream, out, part);
    hipLaunchKernelGGL(std_final, dim3(8), dim3(256), 0, stream, part, scalev);
    hipLaunchKernelGGL(apply_scale, dim3(NTOT / 4 / 256), dim3(256), 0, stream, out, scalev);
}

// Round 4
// 201.807 us; speedup vs baseline: 1.5625x; 1.1477x over previous
//
#include <hip/hip_runtime.h>
#include <math.h>

#define NTOT 8388608   // 2^23 = 32*4096*64
#define N1   2048
#define N2   4096
#define BB   32
#define LL   4096
#define DD   64

enum { M_NONE = 0, M_TW = 1, M_SCALE = 4 };

__device__ inline float2 cmul(float2 a, float2 b) {
    return make_float2(a.x*b.x - a.y*b.y, a.x*b.y + a.y*b.x);
}
__device__ inline float2 cmul_conj(float2 a, float2 b) {   // a * conj(b)
    return make_float2(a.x*b.x + a.y*b.y, a.y*b.x - a.x*b.y);
}
__device__ inline float2 cadd(float2 a, float2 b){ return make_float2(a.x+b.x, a.y+b.y); }
__device__ inline float2 csub(float2 a, float2 b){ return make_float2(a.x-b.x, a.y-b.y); }
__device__ inline float2 mul_pi(float2 a){ return make_float2(-a.y, a.x); }   // * i
__device__ inline float2 mul_mi(float2 a){ return make_float2(a.y, -a.x); }   // * -i
__device__ inline int pidx(int a){ return a + (a >> 4); }                     // float2 LDS pad

// DFT8: y_k = sum_m x_m W8^{+-km}
template<bool INV>
__device__ inline void dft8(const float2* x, float2* y) {
    const float C = 0.70710678118654752f;
    float2 t0=cadd(x[0],x[4]), t1=cadd(x[1],x[5]), t2=cadd(x[2],x[6]), t3=cadd(x[3],x[7]);
    float2 u0=csub(x[0],x[4]), u1=csub(x[1],x[5]), u2=csub(x[2],x[6]), u3=csub(x[3],x[7]);
    if (!INV) {
        u1 = make_float2(C*(u1.x+u1.y), C*(u1.y-u1.x));
        u2 = mul_mi(u2);
        u3 = make_float2(C*(u3.y-u3.x), -C*(u3.x+u3.y));
    } else {
        u1 = make_float2(C*(u1.x-u1.y), C*(u1.y+u1.x));
        u2 = mul_pi(u2);
        u3 = make_float2(-C*(u3.x+u3.y), C*(u3.x-u3.y));
    }
    {
        float2 s0=cadd(t0,t2), s1=cadd(t1,t3), d0=csub(t0,t2);
        float2 d1 = INV ? mul_pi(csub(t1,t3)) : mul_mi(csub(t1,t3));
        y[0]=cadd(s0,s1); y[4]=csub(s0,s1); y[2]=cadd(d0,d1); y[6]=csub(d0,d1);
    }
    {
        float2 s0=cadd(u0,u2), s1=cadd(u1,u3), d0=csub(u0,u2);
        float2 d1 = INV ? mul_pi(csub(u1,u3)) : mul_mi(csub(u1,u3));
        y[1]=cadd(s0,s1); y[5]=csub(s0,s1); y[3]=cadd(d0,d1); y[7]=csub(d0,d1);
    }
}

// inverse DFT8 with x[4..7] == 0 (Hilbert-zeroed upper half)
__device__ inline void dft8_h0_inv(const float2* x, float2* y) {
    const float C = 0.70710678118654752f;
    float2 u1 = make_float2(C*(x[1].x - x[1].y), C*(x[1].y + x[1].x));
    float2 u2 = mul_pi(x[2]);
    float2 u3 = make_float2(-C*(x[3].x + x[3].y), C*(x[3].x - x[3].y));
    {
        float2 s0=cadd(x[0],x[2]), s1=cadd(x[1],x[3]), d0=csub(x[0],x[2]);
        float2 d1 = mul_pi(csub(x[1],x[3]));
        y[0]=cadd(s0,s1); y[4]=csub(s0,s1); y[2]=cadd(d0,d1); y[6]=csub(d0,d1);
    }
    {
        float2 s0=cadd(x[0],u2), s1=cadd(u1,u3), d0=csub(x[0],u2);
        float2 d1 = mul_pi(csub(u1,u3));
        y[1]=cadd(s0,s1); y[5]=csub(s0,s1); y[3]=cadd(d0,d1); y[7]=csub(d0,d1);
    }
}

template<bool INV>
__device__ inline void dft4(const float2* u, float2* y) {
    float2 s0=cadd(u[0],u[2]), s1=cadd(u[1],u[3]), d0=csub(u[0],u[2]);
    float2 d1 = INV ? mul_pi(csub(u[1],u[3])) : mul_mi(csub(u[1],u[3]));
    y[0]=cadd(s0,s1); y[2]=csub(s0,s1); y[1]=cadd(d0,d1); y[3]=csub(d0,d1);
}

// y_k *= W^{+-ps*k}: ONE gather for w^1, powers via cmul tree (avoids 6 divergent gathers)
template<bool INV, int SH>
__device__ inline void twiddle8(float2* y, int ps, const float2* __restrict__ T1t) {
    float2 w1 = T1t[(ps << SH) & 4095];
    float2 w2 = cmul(w1, w1);
    float2 w3 = cmul(w2, w1);
    float2 w4 = cmul(w2, w2);
    float2 w5 = cmul(w4, w1);
    float2 w6 = cmul(w3, w3);
    float2 w7 = cmul(w4, w3);
    if (!INV) {
        y[1]=cmul(y[1],w1); y[2]=cmul(y[2],w2); y[3]=cmul(y[3],w3);
        y[4]=cmul(y[4],w4); y[5]=cmul(y[5],w5); y[6]=cmul(y[6],w6); y[7]=cmul(y[7],w7);
    } else {
        y[1]=cmul_conj(y[1],w1); y[2]=cmul_conj(y[2],w2); y[3]=cmul_conj(y[3],w3);
        y[4]=cmul_conj(y[4],w4); y[5]=cmul_conj(y[5],w5); y[6]=cmul_conj(y[6],w6); y[7]=cmul_conj(y[7],w7);
    }
}

// ---------------- twiddle tables ----------------
__global__ __launch_bounds__(256) void gen_tables(float2* T1, float2* T2) {
    int j = blockIdx.x * 256 + threadIdx.x;
    if (j < 4096) {
        double ang = -2.0 * M_PI * (double)j / 4096.0;
        T1[j] = make_float2((float)cos(ang), (float)sin(ang));
    } else if (j < 4096 + 2048) {
        int b = j - 4096;
        double ang = -2.0 * M_PI * (double)b / 8388608.0;
        T2[b] = make_float2((float)cos(ang), (float)sin(ang));
    }
}

// W_2^23^{t} from split tables (t < 2^23)
__device__ inline float2 wbig(int t, const float2* __restrict__ T1t, const float2* __restrict__ T2t) {
    return cmul(T1t[t >> 11], T2t[t & 2047]);
}

// ---------------- 4096-point radix-8 Stockham, one row per block ----------------
template<bool INV, int MODE>
__global__ __launch_bounds__(512) void fft4096(float2* data,
                                               const float2* __restrict__ T1t,
                                               const float2* __restrict__ T2t) {
    __shared__ float2 S[4352];
    const int t = threadIdx.x;
    const int r = blockIdx.x;
    float2* base = data + (size_t)r * 4096;

    float2 x[8], y[8];
    #pragma unroll
    for (int m = 0; m < 8; ++m) x[m] = base[t + 512*m];

    #pragma unroll
    for (int st = 0; st < 3; ++st) {
        const int s = 1 << (3*st);
        const int q = t & (s - 1);
        const int ps = t - q;
        dft8<INV>(x, y);
        twiddle8<INV, 0>(y, ps, T1t);
        if (st) __syncthreads();
        #pragma unroll
        for (int k = 0; k < 8; ++k) S[pidx(8*ps + q + k*s)] = y[k];
        __syncthreads();
        #pragma unroll
        for (int m = 0; m < 8; ++m) x[m] = S[pidx(t + 512*m)];
    }
    dft8<INV>(x, y);

    if (MODE == M_TW) {
        // w(r*(t+512k)) = w(r*t) * w(512r)^k ; w(512r) is block-uniform (broadcast load)
        float2 wb    = wbig(r * t, T1t, T2t);          // per-lane, 2 gathers total
        float2 wstep = wbig(512 * r, T1t, T2t);        // uniform
        #pragma unroll
        for (int k = 0; k < 8; ++k) {
            int o = t + 512*k;
            base[o] = INV ? cmul_conj(y[k], wb) : cmul(y[k], wb);
            wb = INV ? cmul_conj(wb, wstep) : cmul(wb, wstep);
        }
    } else {
        #pragma unroll
        for (int k = 0; k < 8; ++k) {
            int o = t + 512*k;
            float2 v = y[k];
            if (MODE == M_SCALE) {
                const float sc = 1.f / 8388608.f;
                v.x *= sc; v.y *= sc;
            }
            base[o] = v;
        }
    }
}

// ------- fused middle: fwd 2048 FFT + Hilbert mask + inv 2048 FFT + conj four-step twiddle -------
// rows r in [0,4096); global freq of row element i is k = i*N2 + r
__global__ __launch_bounds__(256) void fftmid(float2* data,
                                              const float2* __restrict__ T1t,
                                              const float2* __restrict__ T2t) {
    __shared__ float2 S[2176];
    const int t = threadIdx.x;
    const int r = blockIdx.x;
    float2* base = data + (size_t)r * 2048;

    float2 x[8], y[8];
    #pragma unroll
    for (int m = 0; m < 8; ++m) x[m] = base[t + 256*m];

    // ---- forward: radix-8 stages s=1,8,64 ----
    #pragma unroll
    for (int st = 0; st < 3; ++st) {
        const int s = 1 << (3*st);
        const int q = t & (s - 1);
        const int ps = t - q;
        dft8<false>(x, y);
        twiddle8<false, 1>(y, ps, T1t);
        if (st) __syncthreads();
        #pragma unroll
        for (int k = 0; k < 8; ++k) S[pidx(8*ps + q + k*s)] = y[k];
        __syncthreads();
        if (st < 2) {
            #pragma unroll
            for (int m = 0; m < 8; ++m) x[m] = S[pidx(t + 256*m)];
        }
    }
    // ---- forward final: radix-4, s=512, ids t and t+256, ps=0 ----
    float2 xa[4], xb[4], ya[4], yb[4];
    #pragma unroll
    for (int m = 0; m < 4; ++m) {
        xa[m] = S[pidx(t + 512*m)];
        xb[m] = S[pidx(t + 256 + 512*m)];
    }
    dft4<false>(xa, ya);
    dft4<false>(xb, yb);
    __syncthreads();                           // WAR before mask writes
    // ---- Hilbert mask at natural order; only o <= 1024 survives ----
    #pragma unroll
    for (int k = 0; k < 4; ++k) {
        int o = t + 512*k;                     // global freq = o*N2 + r
        if (o < 1024) {
            float h = (o == 0 && r == 0) ? 1.f : 2.f;
            S[pidx(o)] = make_float2(ya[k].x * h, ya[k].y * h);
        } else if (o == 1024) {                // t==0, k==2
            S[pidx(1024)] = (r == 0) ? ya[k] : make_float2(0.f, 0.f);
        }
        int o2 = o + 256;                      // never 0 or 1024
        if (o2 < 1024) S[pidx(o2)] = make_float2(yb[k].x * 2.f, yb[k].y * 2.f);
    }
    __syncthreads();
    // ---- inverse stage 0 (s=1, ps=t): upper half is zero ----
    #pragma unroll
    for (int m = 0; m < 4; ++m) x[m] = S[pidx(t + 256*m)];
    dft8_h0_inv(x, y);
    if (t == 0) {                              // corner: freq o=1024 (h=1, r==0 only)
        float2 c = S[pidx(1024)];
        #pragma unroll
        for (int k = 0; k < 8; ++k) {
            if (k & 1) { y[k].x -= c.x; y[k].y -= c.y; }
            else       { y[k].x += c.x; y[k].y += c.y; }
        }
    }
    twiddle8<true, 1>(y, t, T1t);
    __syncthreads();                           // WAR vs masked reads
    #pragma unroll
    for (int k = 0; k < 8; ++k) S[pidx(8*t + k)] = y[k];
    __syncthreads();
    // ---- inverse stages s=8,64 ----
    #pragma unroll
    for (int st = 1; st < 3; ++st) {
        const int s = 1 << (3*st);
        const int q = t & (s - 1);
        const int ps = t - q;
        #pragma unroll
        for (int m = 0; m < 8; ++m) x[m] = S[pidx(t + 256*m)];
        dft8<true>(x, y);
        twiddle8<true, 1>(y, ps, T1t);
        __syncthreads();
        #pragma unroll
        for (int k = 0; k < 8; ++k) S[pidx(8*ps + q + k*s)] = y[k];
        __syncthreads();
    }
    // ---- inverse final: radix-4 + conj four-step twiddle + store ----
    #pragma unroll
    for (int m = 0; m < 4; ++m) {
        xa[m] = S[pidx(t + 512*m)];
        xb[m] = S[pidx(t + 256 + 512*m)];
    }
    dft4<true>(xa, ya);
    dft4<true>(xb, yb);
    {
        // w(r*(t+512k)) = w(rt)*w(512r)^k ; second lattice offset by w(256r). Uniform steps.
        float2 wka   = wbig(r * t, T1t, T2t);          // per-lane, 2 gathers
        float2 w256  = wbig(256 * r, T1t, T2t);        // uniform
        float2 w512  = cmul(w256, w256);               // uniform
        float2 wkb   = cmul(wka, w256);
        #pragma unroll
        for (int k = 0; k < 4; ++k) {
            int o = t + 512*k;
            base[o]       = cmul_conj(ya[k], wka);
            base[o + 256] = cmul_conj(yb[k], wkb);
            wka = cmul(wka, w512);
            wkb = cmul(wkb, w512);
        }
    }
}

// ---------------- transposes ----------------
__global__ __launch_bounds__(256) void k_pre(const float* __restrict__ x, float2* __restrict__ A) {
    __shared__ float tile[32][33];
    int c0 = blockIdx.x * 32;   // n1 tile
    int r0 = blockIdx.y * 32;   // n2 tile
    int tx = threadIdx.x, ty = threadIdx.y;
    #pragma unroll
    for (int j = 0; j < 32; j += 8)
        tile[ty + j][tx] = x[(size_t)(r0 + ty + j) * N1 + c0 + tx];
    __syncthreads();
    #pragma unroll
    for (int j = 0; j < 32; j += 8) {
        float v = tile[tx][ty + j];
        A[(size_t)(c0 + ty + j) * N2 + r0 + tx] = make_float2(fmaxf(v, 0.f), fmaxf(-v, 0.f));
    }
}

__global__ __launch_bounds__(256) void k_trans(const float2* __restrict__ in, float2* __restrict__ out,
                                               int inCols, int inRows) {
    __shared__ float2 tile[32][33];
    int c0 = blockIdx.x * 32;
    int r0 = blockIdx.y * 32;
    int tx = threadIdx.x, ty = threadIdx.y;
    #pragma unroll
    for (int j = 0; j < 32; j += 8)
        tile[ty + j][tx] = in[(size_t)(r0 + ty + j) * inCols + c0 + tx];
    __syncthreads();
    #pragma unroll
    for (int j = 0; j < 32; j += 8)
        out[(size_t)(c0 + ty + j) * inRows + r0 + tx] = tile[tx][ty + j];
}

__global__ __launch_bounds__(256) void k_post(const float2* __restrict__ A, const float* __restrict__ x,
                                              float* __restrict__ out) {
    __shared__ float2 tile[32][33];
    int c0 = blockIdx.x * 32;   // n2 tile
    int r0 = blockIdx.y * 32;   // n1 tile
    int tx = threadIdx.x, ty = threadIdx.y;
    #pragma unroll
    for (int j = 0; j < 32; j += 8)
        tile[ty + j][tx] = A[(size_t)(r0 + ty + j) * N2 + c0 + tx];
    __syncthreads();
    #pragma unroll
    for (int j = 0; j < 32; j += 8) {
        int n2 = c0 + ty + j;
        int n1 = r0 + tx;
        size_t n = (size_t)n2 * N1 + n1;
        float2 w = tile[tx][ty + j];
        float xv = x[n];
        float up = fmaxf(xv, 0.f);
        float dn = fmaxf(-xv, 0.f);
        float hu = w.y - dn;          // H(up)
        float hd = up - w.x;          // H(down)
        float em = sqrtf(up*up + hu*hu);
        float en = sqrtf(dn*dn + hd*hd);
        float avg = 0.5f * (em - en);
        out[n]        = xv - avg;
        out[NTOT + n] = avg;
    }
}

// ---------------- std over L (ddof=1), then scale imf ----------------
__global__ __launch_bounds__(256) void std_partial(const float* __restrict__ imf, float* __restrict__ part) {
    int blk = blockIdx.x;
    int b   = blk >> 4;
    int ch  = blk & 15;
    int d   = threadIdx.x & 63;
    int lw  = threadIdx.x >> 6;
    float s1 = 0.f, s2 = 0.f;
    const float* base = imf + (size_t)b * LL * DD;
    for (int i = 0; i < 64; ++i) {
        int l = ch * 256 + lw * 64 + i;
        float v = base[(size_t)l * DD + d];
        s1 += v;
        s2 += v * v;
    }
    __shared__ float r1[4][64];
    __shared__ float r2[4][64];
    r1[lw][d] = s1; r2[lw][d] = s2;
    __syncthreads();
    if (lw == 0) {
        s1 = r1[0][d] + r1[1][d] + r1[2][d] + r1[3][d];
        s2 = r2[0][d] + r2[1][d] + r2[2][d] + r2[3][d];
        int pi = blk * 64 + d;
        part[pi] = s1;
        part[BB * 16 * 64 + pi] = s2;
    }
}

__global__ __launch_bounds__(256) void std_final(const float* __restrict__ part, float* __restrict__ scalev) {
    int g = blockIdx.x * 256 + threadIdx.x;
    int b = g >> 6, d = g & 63;
    float s1 = 0.f, s2 = 0.f;
    for (int ch = 0; ch < 16; ++ch) {
        int pi = (b * 16 + ch) * 64 + d;
        s1 += part[pi];
        s2 += part[BB * 16 * 64 + pi];
    }
    float mean = s1 / (float)LL;
    float var  = (s2 - (float)LL * mean * mean) / (float)(LL - 1);
    var = fmaxf(var, 0.f);
    scalev[g] = 1.f / (sqrtf(var) + 0.01f);
}

__global__ __launch_bounds__(256) void apply_scale(float* __restrict__ out, const float* __restrict__ scalev) {
    size_t i = ((size_t)blockIdx.x * 256 + threadIdx.x) * 4;
    float4 v = *(float4*)(out + i);
    int b = (int)(i >> 18);
    int d = (int)(i & 63);
    const float* sc = scalev + b * 64;
    v.x *= sc[d];
    v.y *= sc[d + 1];
    v.z *= sc[d + 2];
    v.w *= sc[d + 3];
    *(float4*)(out + i) = v;
}

// ---------------- launch ----------------
extern "C" void kernel_launch(void* const* d_in, const int* in_sizes, int n_in,
                              void* d_out, int out_size, void* d_ws, size_t ws_size,
                              hipStream_t stream) {
    const float* x = (const float*)d_in[0];
    float* out = (float*)d_out;
    char* w = (char*)d_ws;

    float2* T1     = (float2*)w;
    float2* T2     = (float2*)(w + 32 * 1024);
    float*  part   = (float*)(w + 48 * 1024);
    float*  scalev = (float*)(w + 320 * 1024);
    float2* A      = (float2*)(w + (1 << 20));
    float2* Bbuf   = (float2*)d_out;

    hipLaunchKernelGGL(gen_tables, dim3(24), dim3(256), 0, stream, T1, T2);

    hipLaunchKernelGGL(k_pre, dim3(N1/32, N2/32), dim3(32, 8), 0, stream, x, A);
    hipLaunchKernelGGL((fft4096<false, M_TW>), dim3(N1), dim3(512), 0, stream, A, T1, T2);
    hipLaunchKernelGGL(k_trans, dim3(N2/32, N1/32), dim3(32, 8), 0, stream, A, Bbuf, N2, N1);
    hipLaunchKernelGGL(fftmid, dim3(N2), dim3(256), 0, stream, Bbuf, T1, T2);
    hipLaunchKernelGGL(k_trans, dim3(N1/32, N2/32), dim3(32, 8), 0, stream, Bbuf, A, N1, N2);
    hipLaunchKernelGGL((fft4096<true, M_SCALE>), dim3(N1), dim3(512), 0, stream, A, T1, T2);
    hipLaunchKernelGGL(k_post, dim3(N2/32, N1/32), dim3(32, 8), 0, stream, A, x, out);

    hipLaunchKernelGGL(std_partial, dim3(BB * 16), dim3(256), 0, stream, out, part);
    hipLaunchKernelGGL(std_final, dim3(8), dim3(256), 0, stream, part, scalev);
    hipLaunchKernelGGL(apply_scale, dim3(NTOT / 4 / 256), dim3(256), 0, stream, out, scalev);
}